// Round 8
// baseline (432.148 us; speedup 1.0000x reference)
//
#include <hip/hip_runtime.h>

typedef float f32x4 __attribute__((ext_vector_type(4)));

#define NEG_SLOPE 0.2f
#define NEG_INF   -1e9f

// ---------------------------------------------------------------------------
// Kernel 1 (fused): edge-record prep + node embedding.
// Blocks [0, nb_edge): rec[e] = { msg1[0..7] } — 32 B record. Lane i writes
// 32 B contiguous, so adjacent lanes complete full 64 B lines (no RMW).
// 32 B records keep the whole gather pool (~200 MB) Infinity-Cache-resident.
// Blocks [nb_edge, ..): h_a[1+n] = tf[n]@W_emb + b_emb ; t0[1+n] = h.(Wg@a_src)
// ---------------------------------------------------------------------------
__global__ void prep_embed(const float* __restrict__ fdg,
                           const float* __restrict__ rij,
                           const float* __restrict__ W_dist,
                           const float* __restrict__ b_dist,
                           const float* __restrict__ W_gat,
                           const float* __restrict__ a_src,
                           const float* __restrict__ tf,
                           const float* __restrict__ W_emb,
                           const float* __restrict__ b_emb,
                           float* __restrict__ rec,
                           float* __restrict__ h_a,
                           float* __restrict__ h_b,
                           float* __restrict__ t0,
                           float* __restrict__ t1,
                           int E, int N, int nb_edge) {
    __shared__ float sW[72];    // W_dist (edge) or W_emb (node)
    __shared__ float sb[8];     // b_dist (edge) or b_emb (node)
    __shared__ float sWg[64];
    __shared__ float s_vec[8];  // Wg@a_src (node blocks only)
    int tid = threadIdx.x;
    bool edge_block = (blockIdx.x < nb_edge);
    if (edge_block) {
        if (tid < 72) sW[tid] = W_dist[tid];
        else if (tid < 80) sb[tid - 72] = b_dist[tid - 72];
    } else {
        if (tid < 64) sW[tid] = W_emb[tid];
        else if (tid < 72) sb[tid - 64] = b_emb[tid - 64];
        if (tid >= 128 && tid < 192) sWg[tid - 128] = W_gat[tid - 128];
    }
    __syncthreads();
    if (!edge_block && tid < 8) {
        float s = 0.f;
        #pragma unroll
        for (int j = 0; j < 8; ++j) s += sWg[tid * 8 + j] * a_src[j];
        s_vec[tid] = s;
    }
    __syncthreads();

    if (edge_block) {
        int e = blockIdx.x * blockDim.x + tid;
        if (e >= E) return;
        const f32x4* fr = reinterpret_cast<const f32x4*>(fdg + (size_t)e * 8);
        f32x4 g0 = fr[0], g1 = fr[1];
        float rv = rij[e];
        float msg[8];
        #pragma unroll
        for (int j = 0; j < 8; ++j) {
            float s = sb[j];
            #pragma unroll
            for (int i = 0; i < 4; ++i) s += g0[i] * sW[i * 8 + j];
            #pragma unroll
            for (int i = 0; i < 4; ++i) s += g1[i] * sW[(4 + i) * 8 + j];
            s += rv * sW[64 + j];
            msg[j] = s;
        }
        f32x4* op = reinterpret_cast<f32x4*>(rec + (size_t)e * 8);
        f32x4 m0 = {msg[0], msg[1], msg[2], msg[3]};
        f32x4 m1 = {msg[4], msg[5], msg[6], msg[7]};
        op[0] = m0; op[1] = m1;                     // 32 B, lane-contiguous
    } else {
        int n = (blockIdx.x - nb_edge) * blockDim.x + tid;
        if (n >= N) return;
        if (n == 0) {
            #pragma unroll
            for (int j = 0; j < 8; ++j) { h_a[j] = 0.f; h_b[j] = 0.f; }
            t0[0] = 0.f;
            t1[0] = 0.f;
        }
        const f32x4* tfr = reinterpret_cast<const f32x4*>(tf + (size_t)n * 8);
        f32x4 a = tfr[0], b = tfr[1];
        float x[8] = {a[0], a[1], a[2], a[3], b[0], b[1], b[2], b[3]};
        float out[8];
        #pragma unroll
        for (int j = 0; j < 8; ++j) out[j] = sb[j];
        #pragma unroll
        for (int i = 0; i < 8; ++i)
            #pragma unroll
            for (int j = 0; j < 8; ++j)
                out[j] += x[i] * sW[i * 8 + j];
        float t = 0.f;
        #pragma unroll
        for (int p = 0; p < 8; ++p) t += out[p] * s_vec[p];
        t0[n + 1] = t;
        f32x4* hr = reinterpret_cast<f32x4*>(h_a + (size_t)(n + 1) * 8);
        f32x4 o0 = {out[0], out[1], out[2], out[3]};
        f32x4 o1 = {out[4], out[5], out[6], out[7]};
        hr[0] = o0;
        hr[1] = o1;
    }
}

// ---------------------------------------------------------------------------
// Per-node finish: logit -> softmax -> aggregate -> store (+optional t1)
// ---------------------------------------------------------------------------
__device__ __forceinline__ void finish_node(const float msg[8], float t_se, float em,
                                            bool has, bool vk, int lane, int node,
                                            const float* __restrict__ sWg,
                                            const float* __restrict__ s_as,
                                            float* __restrict__ h_next,
                                            float* __restrict__ t_next) {
    float ee = t_se + em;
    ee = (ee >= 0.f) ? ee : NEG_SLOPE * ee;            // leaky relu
    float e = has ? ee : (vk ? NEG_INF : -3e38f);      // pad / lane mask

    float m = e;
    #pragma unroll
    for (int off = 16; off; off >>= 1) m = fmaxf(m, __shfl_xor(m, off, 32));
    float p = vk ? expf(e - m) : 0.f;
    float denom = p;
    #pragma unroll
    for (int off = 16; off; off >>= 1) denom += __shfl_xor(denom, off, 32);
    float alpha = p / denom;

    float agg[8];
    #pragma unroll
    for (int j = 0; j < 8; ++j) agg[j] = alpha * msg[j];
    #pragma unroll
    for (int off = 16; off; off >>= 1)
        #pragma unroll
        for (int j = 0; j < 8; ++j) agg[j] += __shfl_xor(agg[j], off, 32);

    if (lane < 8) {
        float o = 0.f;
        #pragma unroll
        for (int i = 0; i < 8; ++i) o += agg[i] * sWg[i * 8 + lane];
        o = (o > 0.f) ? o : (expf(o) - 1.f);           // elu
        h_next[(size_t)(node + 1) * 8 + lane] = o;
        if (t_next) {
            float tv = o * s_as[lane];
            tv += __shfl_xor(tv, 1, 32);
            tv += __shfl_xor(tv, 2, 32);
            tv += __shfl_xor(tv, 4, 32);
            if (lane == 0) t_next[node + 1] = tv;
        }
    }
}

// ---------------------------------------------------------------------------
// Kernel 2: GAT iteration 1 (record path). One node per 32-lane group.
// Per slot: 32 B record gather (L3-resident pool) + t0[se] (L2-resident);
// em recomputed in-register (same FMA order as before -> bit-identical).
// ---------------------------------------------------------------------------
__global__ void gat_iter1_rec(const float* __restrict__ t0,
                              float* __restrict__ h1,
                              float* __restrict__ t1,
                              const int* __restrict__ b_scope,
                              const int* __restrict__ se_env,
                              const float* __restrict__ rec,
                              const float* __restrict__ W_gat,
                              const float* __restrict__ a_src,
                              const float* __restrict__ a_dst,
                              int N, int K) {
    __shared__ float sWg[64];
    __shared__ float s_as[8];
    __shared__ float s_ad[8];
    int tid = threadIdx.x;
    if (tid < 64) sWg[tid] = W_gat[tid];
    __syncthreads();
    if (tid < 8) {
        float s = 0.f;
        #pragma unroll
        for (int j = 0; j < 8; ++j) s += sWg[tid * 8 + j] * a_src[j];
        s_as[tid] = s;
    } else if (tid < 16) {
        int i = tid - 8;
        float s = 0.f;
        #pragma unroll
        for (int j = 0; j < 8; ++j) s += sWg[i * 8 + j] * a_dst[j];
        s_ad[i] = s;
    }
    __syncthreads();

    int node = blockIdx.x * 8 + (tid >> 5);
    int lane = tid & 31;
    if (node >= N) return;
    bool vk = (lane < K);

    int bs = 0, se = 0;
    if (vk) {
        bs = b_scope[(size_t)node * K + lane];
        se = se_env[(size_t)node * K + lane];
    }
    bool has = vk && (bs > 0);
    float t_se = vk ? t0[se] : 0.f;

    f32x4 m0 = {0,0,0,0}, m1 = {0,0,0,0};
    if (has) {
        const f32x4* rp = reinterpret_cast<const f32x4*>(rec + (size_t)(bs - 1) * 8);
        m0 = rp[0]; m1 = rp[1];
    }
    float msg[8] = {m0[0], m0[1], m0[2], m0[3], m1[0], m1[1], m1[2], m1[3]};
    float em = 0.f;
    #pragma unroll
    for (int j = 0; j < 8; ++j) em += msg[j] * s_ad[j];

    finish_node(msg, t_se, em, has, vk, lane, node, sWg, s_as, h1, t1);
}

// ---------------------------------------------------------------------------
// Kernel 2' (fallback, no workspace for rec): direct gathers.
// ---------------------------------------------------------------------------
__global__ void gat_iter1_fb(const float* __restrict__ t0,
                             float* __restrict__ h1,
                             float* __restrict__ t1,
                             const int* __restrict__ b_scope,
                             const int* __restrict__ se_env,
                             const float* __restrict__ fdg,
                             const float* __restrict__ rij,
                             const float* __restrict__ W_dist,
                             const float* __restrict__ b_dist,
                             const float* __restrict__ W_gat,
                             const float* __restrict__ a_src,
                             const float* __restrict__ a_dst,
                             int N, int K) {
    __shared__ float sWg[64];
    __shared__ float s_as[8];
    __shared__ float s_ad[8];
    __shared__ float sWd[72];
    __shared__ float sbd[8];
    int tid = threadIdx.x;
    if (tid < 64) sWg[tid] = W_gat[tid];
    if (tid >= 64 && tid < 136) sWd[tid - 64] = W_dist[tid - 64];
    if (tid >= 136 && tid < 144) sbd[tid - 136] = b_dist[tid - 136];
    __syncthreads();
    if (tid < 8) {
        float s = 0.f;
        #pragma unroll
        for (int j = 0; j < 8; ++j) s += sWg[tid * 8 + j] * a_src[j];
        s_as[tid] = s;
    } else if (tid < 16) {
        int i = tid - 8;
        float s = 0.f;
        #pragma unroll
        for (int j = 0; j < 8; ++j) s += sWg[i * 8 + j] * a_dst[j];
        s_ad[i] = s;
    }
    __syncthreads();

    int node = blockIdx.x * 8 + (tid >> 5);
    int lane = tid & 31;
    if (node >= N) return;
    bool vk = (lane < K);

    int bs = 0, se = 0;
    if (vk) {
        bs = b_scope[(size_t)node * K + lane];
        se = se_env[(size_t)node * K + lane];
    }
    bool has = vk && (bs > 0);
    float t_se = vk ? t0[se] : 0.f;

    float msg[8];
    #pragma unroll
    for (int j = 0; j < 8; ++j) msg[j] = 0.f;
    float em = 0.f;
    if (has) {
        const f32x4* fr = reinterpret_cast<const f32x4*>(fdg + (size_t)(bs - 1) * 8);
        f32x4 g0 = fr[0], g1 = fr[1];
        float rv = rij[bs - 1];
        #pragma unroll
        for (int j = 0; j < 8; ++j) {
            float s = sbd[j];
            #pragma unroll
            for (int i = 0; i < 4; ++i) s += g0[i] * sWd[i * 8 + j];
            #pragma unroll
            for (int i = 0; i < 4; ++i) s += g1[i] * sWd[(4 + i) * 8 + j];
            s += rv * sWd[64 + j];
            msg[j] = s;
        }
        #pragma unroll
        for (int j = 0; j < 8; ++j) em += msg[j] * s_ad[j];
    }
    finish_node(msg, t_se, em, has, vk, lane, node, sWg, s_as, h1, t1);
}

// ---------------------------------------------------------------------------
// Kernel 3: GAT iteration 2. TWO nodes per group (2-deep dependent chains
// edge_src[bs-1] -> h1[src], both gathers into cache-resident arrays).
// ---------------------------------------------------------------------------
__global__ void gat_iter2(const float* __restrict__ h1,
                          const float* __restrict__ t1,
                          float* __restrict__ h2,
                          const int* __restrict__ b_scope,
                          const int* __restrict__ se_env,
                          const int* __restrict__ edge_src,
                          const float* __restrict__ W_gat,
                          const float* __restrict__ a_dst,
                          int N, int K) {
    __shared__ float sWg[64];
    __shared__ float s_ad[8];
    int tid = threadIdx.x;
    if (tid < 64) sWg[tid] = W_gat[tid];
    __syncthreads();
    if (tid < 8) {
        float s = 0.f;
        #pragma unroll
        for (int j = 0; j < 8; ++j) s += sWg[tid * 8 + j] * a_dst[j];
        s_ad[tid] = s;
    }
    __syncthreads();

    int lane = tid & 31;
    int g = blockIdx.x * 8 + (tid >> 5);
    int nA = g * 2, nB = g * 2 + 1;
    if (nA >= N) return;
    bool hasBn = (nB < N);
    bool vk = (lane < K);

    int bsA = 0, seA = 0, bsB = 0, seB = 0;
    if (vk) {
        bsA = b_scope[(size_t)nA * K + lane];
        seA = se_env[(size_t)nA * K + lane];
        if (hasBn) {
            bsB = b_scope[(size_t)nB * K + lane];
            seB = se_env[(size_t)nB * K + lane];
        }
    }
    bool hasA = vk && (bsA > 0);
    bool hasB = vk && hasBn && (bsB > 0);

    float tA = vk ? t1[seA] : 0.f;
    float tB = (vk && hasBn) ? t1[seB] : 0.f;

    int srcA = 0, srcB = 0;
    if (hasA) srcA = edge_src[bsA - 1];
    if (hasB) srcB = edge_src[bsB - 1];

    f32x4 a0 = {0,0,0,0}, a1 = {0,0,0,0}, b0 = {0,0,0,0}, b1 = {0,0,0,0};
    if (hasA) {
        const f32x4* mr = reinterpret_cast<const f32x4*>(h1 + (size_t)srcA * 8);
        a0 = mr[0]; a1 = mr[1];
    }
    if (hasB) {
        const f32x4* mr = reinterpret_cast<const f32x4*>(h1 + (size_t)srcB * 8);
        b0 = mr[0]; b1 = mr[1];
    }

    float msgA[8] = {a0[0], a0[1], a0[2], a0[3], a1[0], a1[1], a1[2], a1[3]};
    float emA = 0.f;
    #pragma unroll
    for (int j = 0; j < 8; ++j) emA += msgA[j] * s_ad[j];
    finish_node(msgA, tA, emA, hasA, vk, lane, nA, sWg, nullptr, h2, nullptr);
    if (hasBn) {
        float msgB[8] = {b0[0], b0[1], b0[2], b0[3], b1[0], b1[1], b1[2], b1[3]};
        float emB = 0.f;
        #pragma unroll
        for (int j = 0; j < 8; ++j) emB += msgB[j] * s_ad[j];
        finish_node(msgB, tB, emB, hasB, vk, lane, nB, sWg, nullptr, h2, nullptr);
    }
}

// ---------------------------------------------------------------------------
// Kernel 4: readout  out[b,:] = sum_l h[l_scope[b,l], :]
// ---------------------------------------------------------------------------
__global__ void readout_kernel(const float* __restrict__ h,
                               const int* __restrict__ l_scope,
                               float* __restrict__ out, int B, int L) {
    int gid = blockIdx.x * blockDim.x + threadIdx.x;
    int b = gid >> 3;
    int j = gid & 7;
    if (b >= B) return;
    float s = 0.f;
    for (int l = 0; l < L; ++l) {
        int idx = l_scope[(size_t)b * L + l];
        s += h[(size_t)idx * 8 + j];
    }
    out[(size_t)b * 8 + j] = s;
}

// ---------------------------------------------------------------------------
extern "C" void kernel_launch(void* const* d_in, const int* in_sizes, int n_in,
                              void* d_out, int out_size, void* d_ws, size_t ws_size,
                              hipStream_t stream) {
    const float* tf      = (const float*)d_in[0];
    const float* fdg     = (const float*)d_in[1];
    const float* rij     = (const float*)d_in[2];
    const int* b_scope   = (const int*)d_in[3];
    const int* start_env = (const int*)d_in[4];
    const int* l_scope   = (const int*)d_in[5];
    const int* edge_src  = (const int*)d_in[6];
    const float* W_emb   = (const float*)d_in[7];
    const float* b_emb   = (const float*)d_in[8];
    const float* W_dist  = (const float*)d_in[9];
    const float* b_dist  = (const float*)d_in[10];
    const float* W_gat   = (const float*)d_in[11];
    const float* a_src   = (const float*)d_in[12];
    const float* a_dst   = (const float*)d_in[13];
    float* out = (float*)d_out;

    const int N = in_sizes[0] / 8;          // 204800
    const int E = in_sizes[1] / 8;          // 6144000
    const int K = in_sizes[3] / N;          // 30
    const int L = 50;
    const int B = in_sizes[5] / L;          // 4096

    size_t rec_f = (size_t)E * 8;           // 32 B records (floats)
    size_t need  = (rec_f + 2 * (size_t)(N + 1) * 8 + 2 * (size_t)(N + 1)) * 4;
    bool use_rec = (ws_size >= need);

    float* base = (float*)d_ws;
    float* rec  = base;
    size_t off  = use_rec ? rec_f : 0;
    float* h_a  = base + off;  off += (size_t)(N + 1) * 8;
    float* h_b  = base + off;  off += (size_t)(N + 1) * 8;
    float* t0v  = base + off;  off += (size_t)(N + 1);
    float* t1v  = base + off;

    const int nb_edge = (E + 255) / 256;
    const int nb_node = (N + 255) / 256;

    if (use_rec) {
        prep_embed<<<nb_edge + nb_node, 256, 0, stream>>>(
            fdg, rij, W_dist, b_dist, W_gat, a_src,
            tf, W_emb, b_emb, rec, h_a, h_b, t0v, t1v, E, N, nb_edge);
        gat_iter1_rec<<<(N + 7) / 8, 256, 0, stream>>>(t0v, h_b, t1v,
                                                       b_scope, start_env, rec,
                                                       W_gat, a_src, a_dst, N, K);
    } else {
        prep_embed<<<nb_node, 256, 0, stream>>>(
            fdg, rij, W_dist, b_dist, W_gat, a_src,
            tf, W_emb, b_emb, rec, h_a, h_b, t0v, t1v, 0, N, 0);
        gat_iter1_fb<<<(N + 7) / 8, 256, 0, stream>>>(t0v, h_b, t1v,
                                                      b_scope, start_env,
                                                      fdg, rij,
                                                      W_dist, b_dist, W_gat,
                                                      a_src, a_dst, N, K);
    }

    const int g2_blocks = ((N + 1) / 2 + 7) / 8;
    gat_iter2<<<g2_blocks, 256, 0, stream>>>(h_b, t1v, h_a, b_scope, start_env,
                                             edge_src, W_gat, a_dst, N, K);

    readout_kernel<<<(B * 8 + 255) / 256, 256, 0, stream>>>(h_a, l_scope, out, B, L);
}

// Round 9
// 406.732 us; speedup vs baseline: 1.0625x; 1.0625x over previous
//
#include <hip/hip_runtime.h>

typedef float f32x4 __attribute__((ext_vector_type(4)));

#define NEG_SLOPE 0.2f
#define NEG_INF   -1e9f

// ---------------------------------------------------------------------------
// Kernel 1 (fused, 3 block types):
//  type 0 (edge):  rec[e] = msg1[0..7]  (32 B, lane-contiguous, full lines)
//  type 1 (slot):  src_idx[s] = b_scope[s]>0 ? edge_src[b_scope[s]-1] : -1
//                  (the ONLY random edge_src gather; gets prep's L2)
//  type 2 (node):  h_a[1+n] = tf[n]@W_emb + b_emb ; t0[1+n] = h.(Wg@a_src)
// Edge and slot blocks are interleaved 1:1 (E == N*K here) to blend the
// streaming-BW-bound and request-rate-bound regimes on the fabric.
// ---------------------------------------------------------------------------
__global__ void prep_embed(const float* __restrict__ fdg,
                           const float* __restrict__ rij,
                           const int* __restrict__ b_scope,
                           const int* __restrict__ edge_src,
                           const float* __restrict__ W_dist,
                           const float* __restrict__ b_dist,
                           const float* __restrict__ W_gat,
                           const float* __restrict__ a_src,
                           const float* __restrict__ tf,
                           const float* __restrict__ W_emb,
                           const float* __restrict__ b_emb,
                           float* __restrict__ rec,
                           int* __restrict__ src_idx,
                           float* __restrict__ h_a,
                           float* __restrict__ h_b,
                           float* __restrict__ t0,
                           float* __restrict__ t1,
                           int E, int NK, int N,
                           int nb_pair, int nb_edge, int nb_slot) {
    __shared__ float sW[72];    // W_dist (edge) or W_emb (node)
    __shared__ float sb[8];     // b_dist (edge) or b_emb (node)
    __shared__ float sWg[64];
    __shared__ float s_vec[8];  // Wg@a_src (node blocks only)
    int tid = threadIdx.x;
    int bid = blockIdx.x;

    int type, widx;
    if (bid < 2 * nb_pair) {
        type = bid & 1;                 // 0 = edge, 1 = slot (interleaved)
        widx = bid >> 1;
    } else {
        int r = bid - 2 * nb_pair;
        if (r < nb_edge - nb_pair)      { type = 0; widx = nb_pair + r; }
        else {
            r -= (nb_edge - nb_pair);
            if (r < nb_slot - nb_pair)  { type = 1; widx = nb_pair + r; }
            else                        { type = 2; widx = r - (nb_slot - nb_pair); }
        }
    }

    if (type == 0) {
        if (tid < 72) sW[tid] = W_dist[tid];
        else if (tid < 80) sb[tid - 72] = b_dist[tid - 72];
    } else if (type == 2) {
        if (tid < 64) sW[tid] = W_emb[tid];
        else if (tid < 72) sb[tid - 64] = b_emb[tid - 64];
        if (tid >= 128 && tid < 192) sWg[tid - 128] = W_gat[tid - 128];
    }
    __syncthreads();
    if (type == 2 && tid < 8) {
        float s = 0.f;
        #pragma unroll
        for (int j = 0; j < 8; ++j) s += sWg[tid * 8 + j] * a_src[j];
        s_vec[tid] = s;
    }
    __syncthreads();

    if (type == 0) {                    // ---- edge record ----
        int e = widx * 256 + tid;
        if (e >= E) return;
        const f32x4* fr = reinterpret_cast<const f32x4*>(fdg + (size_t)e * 8);
        f32x4 g0 = fr[0], g1 = fr[1];
        float rv = rij[e];
        float msg[8];
        #pragma unroll
        for (int j = 0; j < 8; ++j) {
            float s = sb[j];
            #pragma unroll
            for (int i = 0; i < 4; ++i) s += g0[i] * sW[i * 8 + j];
            #pragma unroll
            for (int i = 0; i < 4; ++i) s += g1[i] * sW[(4 + i) * 8 + j];
            s += rv * sW[64 + j];
            msg[j] = s;
        }
        f32x4* op = reinterpret_cast<f32x4*>(rec + (size_t)e * 8);
        f32x4 m0 = {msg[0], msg[1], msg[2], msg[3]};
        f32x4 m1 = {msg[4], msg[5], msg[6], msg[7]};
        op[0] = m0; op[1] = m1;         // 32 B, lane-contiguous
    } else if (type == 1) {             // ---- slot: src_idx build ----
        int s = widx * 256 + tid;
        if (s >= NK) return;
        int bs = b_scope[s];
        src_idx[s] = (bs > 0) ? edge_src[bs - 1] : -1;
    } else {                            // ---- node embed ----
        int n = widx * 256 + tid;
        if (n >= N) return;
        if (n == 0) {
            #pragma unroll
            for (int j = 0; j < 8; ++j) { h_a[j] = 0.f; h_b[j] = 0.f; }
            t0[0] = 0.f;
            t1[0] = 0.f;
        }
        const f32x4* tfr = reinterpret_cast<const f32x4*>(tf + (size_t)n * 8);
        f32x4 a = tfr[0], b = tfr[1];
        float x[8] = {a[0], a[1], a[2], a[3], b[0], b[1], b[2], b[3]};
        float out[8];
        #pragma unroll
        for (int j = 0; j < 8; ++j) out[j] = sb[j];
        #pragma unroll
        for (int i = 0; i < 8; ++i)
            #pragma unroll
            for (int j = 0; j < 8; ++j)
                out[j] += x[i] * sW[i * 8 + j];
        float t = 0.f;
        #pragma unroll
        for (int p = 0; p < 8; ++p) t += out[p] * s_vec[p];
        t0[n + 1] = t;
        f32x4* hr = reinterpret_cast<f32x4*>(h_a + (size_t)(n + 1) * 8);
        f32x4 o0 = {out[0], out[1], out[2], out[3]};
        f32x4 o1 = {out[4], out[5], out[6], out[7]};
        hr[0] = o0;
        hr[1] = o1;
    }
}

// ---------------------------------------------------------------------------
// Per-node finish: logit -> softmax -> aggregate -> store (+optional t1)
// ---------------------------------------------------------------------------
__device__ __forceinline__ void finish_node(const float msg[8], float t_se, float em,
                                            bool has, bool vk, int lane, int node,
                                            const float* __restrict__ sWg,
                                            const float* __restrict__ s_as,
                                            float* __restrict__ h_next,
                                            float* __restrict__ t_next) {
    float ee = t_se + em;
    ee = (ee >= 0.f) ? ee : NEG_SLOPE * ee;            // leaky relu
    float e = has ? ee : (vk ? NEG_INF : -3e38f);      // pad / lane mask

    float m = e;
    #pragma unroll
    for (int off = 16; off; off >>= 1) m = fmaxf(m, __shfl_xor(m, off, 32));
    float p = vk ? expf(e - m) : 0.f;
    float denom = p;
    #pragma unroll
    for (int off = 16; off; off >>= 1) denom += __shfl_xor(denom, off, 32);
    float alpha = p / denom;

    float agg[8];
    #pragma unroll
    for (int j = 0; j < 8; ++j) agg[j] = alpha * msg[j];
    #pragma unroll
    for (int off = 16; off; off >>= 1)
        #pragma unroll
        for (int j = 0; j < 8; ++j) agg[j] += __shfl_xor(agg[j], off, 32);

    if (lane < 8) {
        float o = 0.f;
        #pragma unroll
        for (int i = 0; i < 8; ++i) o += agg[i] * sWg[i * 8 + lane];
        o = (o > 0.f) ? o : (expf(o) - 1.f);           // elu
        h_next[(size_t)(node + 1) * 8 + lane] = o;
        if (t_next) {
            float tv = o * s_as[lane];
            tv += __shfl_xor(tv, 1, 32);
            tv += __shfl_xor(tv, 2, 32);
            tv += __shfl_xor(tv, 4, 32);
            if (lane == 0) t_next[node + 1] = tv;
        }
    }
}

// ---------------------------------------------------------------------------
// Kernel 2: GAT iteration 1 (record path). One node per 32-lane group.
// Per slot: 32 B record gather (L3-resident pool) + t0[se] (L2-resident);
// em recomputed in-register (same FMA order as prep -> bit-identical).
// ---------------------------------------------------------------------------
__global__ void gat_iter1_rec(const float* __restrict__ t0,
                              float* __restrict__ h1,
                              float* __restrict__ t1,
                              const int* __restrict__ b_scope,
                              const int* __restrict__ se_env,
                              const float* __restrict__ rec,
                              const float* __restrict__ W_gat,
                              const float* __restrict__ a_src,
                              const float* __restrict__ a_dst,
                              int N, int K) {
    __shared__ float sWg[64];
    __shared__ float s_as[8];
    __shared__ float s_ad[8];
    int tid = threadIdx.x;
    if (tid < 64) sWg[tid] = W_gat[tid];
    __syncthreads();
    if (tid < 8) {
        float s = 0.f;
        #pragma unroll
        for (int j = 0; j < 8; ++j) s += sWg[tid * 8 + j] * a_src[j];
        s_as[tid] = s;
    } else if (tid < 16) {
        int i = tid - 8;
        float s = 0.f;
        #pragma unroll
        for (int j = 0; j < 8; ++j) s += sWg[i * 8 + j] * a_dst[j];
        s_ad[i] = s;
    }
    __syncthreads();

    int node = blockIdx.x * 8 + (tid >> 5);
    int lane = tid & 31;
    if (node >= N) return;
    bool vk = (lane < K);

    int bs = 0, se = 0;
    if (vk) {
        bs = b_scope[(size_t)node * K + lane];
        se = se_env[(size_t)node * K + lane];
    }
    bool has = vk && (bs > 0);
    float t_se = vk ? t0[se] : 0.f;

    f32x4 m0 = {0,0,0,0}, m1 = {0,0,0,0};
    if (has) {
        const f32x4* rp = reinterpret_cast<const f32x4*>(rec + (size_t)(bs - 1) * 8);
        m0 = rp[0]; m1 = rp[1];
    }
    float msg[8] = {m0[0], m0[1], m0[2], m0[3], m1[0], m1[1], m1[2], m1[3]};
    float em = 0.f;
    #pragma unroll
    for (int j = 0; j < 8; ++j) em += msg[j] * s_ad[j];

    finish_node(msg, t_se, em, has, vk, lane, node, sWg, s_as, h1, t1);
}

// ---------------------------------------------------------------------------
// Kernel 2' (fallback, no workspace for rec): direct gathers.
// ---------------------------------------------------------------------------
__global__ void gat_iter1_fb(const float* __restrict__ t0,
                             float* __restrict__ h1,
                             float* __restrict__ t1,
                             const int* __restrict__ b_scope,
                             const int* __restrict__ se_env,
                             const float* __restrict__ fdg,
                             const float* __restrict__ rij,
                             const float* __restrict__ W_dist,
                             const float* __restrict__ b_dist,
                             const float* __restrict__ W_gat,
                             const float* __restrict__ a_src,
                             const float* __restrict__ a_dst,
                             int N, int K) {
    __shared__ float sWg[64];
    __shared__ float s_as[8];
    __shared__ float s_ad[8];
    __shared__ float sWd[72];
    __shared__ float sbd[8];
    int tid = threadIdx.x;
    if (tid < 64) sWg[tid] = W_gat[tid];
    if (tid >= 64 && tid < 136) sWd[tid - 64] = W_dist[tid - 64];
    if (tid >= 136 && tid < 144) sbd[tid - 136] = b_dist[tid - 136];
    __syncthreads();
    if (tid < 8) {
        float s = 0.f;
        #pragma unroll
        for (int j = 0; j < 8; ++j) s += sWg[tid * 8 + j] * a_src[j];
        s_as[tid] = s;
    } else if (tid < 16) {
        int i = tid - 8;
        float s = 0.f;
        #pragma unroll
        for (int j = 0; j < 8; ++j) s += sWg[i * 8 + j] * a_dst[j];
        s_ad[i] = s;
    }
    __syncthreads();

    int node = blockIdx.x * 8 + (tid >> 5);
    int lane = tid & 31;
    if (node >= N) return;
    bool vk = (lane < K);

    int bs = 0, se = 0;
    if (vk) {
        bs = b_scope[(size_t)node * K + lane];
        se = se_env[(size_t)node * K + lane];
    }
    bool has = vk && (bs > 0);
    float t_se = vk ? t0[se] : 0.f;

    float msg[8];
    #pragma unroll
    for (int j = 0; j < 8; ++j) msg[j] = 0.f;
    float em = 0.f;
    if (has) {
        const f32x4* fr = reinterpret_cast<const f32x4*>(fdg + (size_t)(bs - 1) * 8);
        f32x4 g0 = fr[0], g1 = fr[1];
        float rv = rij[bs - 1];
        #pragma unroll
        for (int j = 0; j < 8; ++j) {
            float s = sbd[j];
            #pragma unroll
            for (int i = 0; i < 4; ++i) s += g0[i] * sWd[i * 8 + j];
            #pragma unroll
            for (int i = 0; i < 4; ++i) s += g1[i] * sWd[(4 + i) * 8 + j];
            s += rv * sWd[64 + j];
            msg[j] = s;
        }
        #pragma unroll
        for (int j = 0; j < 8; ++j) em += msg[j] * s_ad[j];
    }
    finish_node(msg, t_se, em, has, vk, lane, node, sWg, s_as, h1, t1);
}

// ---------------------------------------------------------------------------
// Kernel 3: GAT iteration 2. TWO nodes per group.
// SRCIDX=true : src read COALESCED from src_idx; only random stream is
//               h1[src] (6.5 MB pool, dedicated L2 -> high hit rate).
// SRCIDX=false: fallback — gathers edge_src[b_scope-1] directly.
// ---------------------------------------------------------------------------
template <bool SRCIDX>
__global__ void gat_iter2(const float* __restrict__ h1,
                          const float* __restrict__ t1,
                          float* __restrict__ h2,
                          const int* __restrict__ src_idx,
                          const int* __restrict__ b_scope,
                          const int* __restrict__ se_env,
                          const int* __restrict__ edge_src,
                          const float* __restrict__ W_gat,
                          const float* __restrict__ a_dst,
                          int N, int K) {
    __shared__ float sWg[64];
    __shared__ float s_ad[8];
    int tid = threadIdx.x;
    if (tid < 64) sWg[tid] = W_gat[tid];
    __syncthreads();
    if (tid < 8) {
        float s = 0.f;
        #pragma unroll
        for (int j = 0; j < 8; ++j) s += sWg[tid * 8 + j] * a_dst[j];
        s_ad[tid] = s;
    }
    __syncthreads();

    int lane = tid & 31;
    int g = blockIdx.x * 8 + (tid >> 5);
    int nA = g * 2, nB = g * 2 + 1;
    if (nA >= N) return;
    bool hasBn = (nB < N);
    bool vk = (lane < K);

    int srcA = -1, srcB = -1, seA = 0, seB = 0;
    if (SRCIDX) {
        if (vk) {
            srcA = src_idx[(size_t)nA * K + lane];
            seA  = se_env[(size_t)nA * K + lane];
            if (hasBn) {
                srcB = src_idx[(size_t)nB * K + lane];
                seB  = se_env[(size_t)nB * K + lane];
            }
        }
    } else {
        int bsA = 0, bsB = 0;
        if (vk) {
            bsA = b_scope[(size_t)nA * K + lane];
            seA = se_env[(size_t)nA * K + lane];
            if (hasBn) {
                bsB = b_scope[(size_t)nB * K + lane];
                seB = se_env[(size_t)nB * K + lane];
            }
        }
        if (vk && bsA > 0) srcA = edge_src[bsA - 1];
        if (vk && hasBn && bsB > 0) srcB = edge_src[bsB - 1];
    }
    bool hasA = vk && (srcA >= 0);
    bool hasB = vk && hasBn && (srcB >= 0);

    float tA = vk ? t1[seA] : 0.f;
    float tB = (vk && hasBn) ? t1[seB] : 0.f;

    f32x4 a0 = {0,0,0,0}, a1 = {0,0,0,0}, b0 = {0,0,0,0}, b1 = {0,0,0,0};
    if (hasA) {
        const f32x4* mr = reinterpret_cast<const f32x4*>(h1 + (size_t)srcA * 8);
        a0 = mr[0]; a1 = mr[1];
    }
    if (hasB) {
        const f32x4* mr = reinterpret_cast<const f32x4*>(h1 + (size_t)srcB * 8);
        b0 = mr[0]; b1 = mr[1];
    }

    float msgA[8] = {a0[0], a0[1], a0[2], a0[3], a1[0], a1[1], a1[2], a1[3]};
    float emA = 0.f;
    #pragma unroll
    for (int j = 0; j < 8; ++j) emA += msgA[j] * s_ad[j];
    finish_node(msgA, tA, emA, hasA, vk, lane, nA, sWg, nullptr, h2, nullptr);
    if (hasBn) {
        float msgB[8] = {b0[0], b0[1], b0[2], b0[3], b1[0], b1[1], b1[2], b1[3]};
        float emB = 0.f;
        #pragma unroll
        for (int j = 0; j < 8; ++j) emB += msgB[j] * s_ad[j];
        finish_node(msgB, tB, emB, hasB, vk, lane, nB, sWg, nullptr, h2, nullptr);
    }
}

// ---------------------------------------------------------------------------
// Kernel 4: readout  out[b,:] = sum_l h[l_scope[b,l], :]
// ---------------------------------------------------------------------------
__global__ void readout_kernel(const float* __restrict__ h,
                               const int* __restrict__ l_scope,
                               float* __restrict__ out, int B, int L) {
    int gid = blockIdx.x * blockDim.x + threadIdx.x;
    int b = gid >> 3;
    int j = gid & 7;
    if (b >= B) return;
    float s = 0.f;
    for (int l = 0; l < L; ++l) {
        int idx = l_scope[(size_t)b * L + l];
        s += h[(size_t)idx * 8 + j];
    }
    out[(size_t)b * 8 + j] = s;
}

// ---------------------------------------------------------------------------
extern "C" void kernel_launch(void* const* d_in, const int* in_sizes, int n_in,
                              void* d_out, int out_size, void* d_ws, size_t ws_size,
                              hipStream_t stream) {
    const float* tf      = (const float*)d_in[0];
    const float* fdg     = (const float*)d_in[1];
    const float* rij     = (const float*)d_in[2];
    const int* b_scope   = (const int*)d_in[3];
    const int* start_env = (const int*)d_in[4];
    const int* l_scope   = (const int*)d_in[5];
    const int* edge_src  = (const int*)d_in[6];
    const float* W_emb   = (const float*)d_in[7];
    const float* b_emb   = (const float*)d_in[8];
    const float* W_dist  = (const float*)d_in[9];
    const float* b_dist  = (const float*)d_in[10];
    const float* W_gat   = (const float*)d_in[11];
    const float* a_src   = (const float*)d_in[12];
    const float* a_dst   = (const float*)d_in[13];
    float* out = (float*)d_out;

    const int N = in_sizes[0] / 8;          // 204800
    const int E = in_sizes[1] / 8;          // 6144000
    const int K = in_sizes[3] / N;          // 30
    const int L = 50;
    const int B = in_sizes[5] / L;          // 4096
    const int NK = N * K;                   // == E here (6,144,000)

    size_t rec_f = (size_t)E * 8;           // 32 B records (floats)
    size_t need  = (rec_f + (size_t)NK      // + src_idx (ints)
                    + 2 * (size_t)(N + 1) * 8 + 2 * (size_t)(N + 1)) * 4;
    bool use_rec = (ws_size >= need);

    float* base = (float*)d_ws;
    float* rec  = base;
    size_t off  = use_rec ? rec_f : 0;
    float* h_a  = base + off;  off += (size_t)(N + 1) * 8;
    float* h_b  = base + off;  off += (size_t)(N + 1) * 8;
    float* t0v  = base + off;  off += (size_t)(N + 1);
    float* t1v  = base + off;  off += (size_t)(N + 1);
    int* src_idx = (int*)(base + off);

    const int nb_edge = (E + 255) / 256;
    const int nb_slot = (NK + 255) / 256;
    const int nb_node = (N + 255) / 256;
    const int nb_pair = (nb_edge < nb_slot) ? nb_edge : nb_slot;

    if (use_rec) {
        const int grid = nb_edge + nb_slot + nb_node;
        prep_embed<<<grid, 256, 0, stream>>>(
            fdg, rij, b_scope, edge_src, W_dist, b_dist, W_gat, a_src,
            tf, W_emb, b_emb, rec, src_idx, h_a, h_b, t0v, t1v,
            E, NK, N, nb_pair, nb_edge, nb_slot);
        gat_iter1_rec<<<(N + 7) / 8, 256, 0, stream>>>(t0v, h_b, t1v,
                                                       b_scope, start_env, rec,
                                                       W_gat, a_src, a_dst, N, K);
        const int g2_blocks = ((N + 1) / 2 + 7) / 8;
        gat_iter2<true><<<g2_blocks, 256, 0, stream>>>(h_b, t1v, h_a,
                                                       src_idx, b_scope, start_env,
                                                       edge_src, W_gat, a_dst, N, K);
    } else {
        // node-embed only (no edge/slot ranges)
        prep_embed<<<nb_node, 256, 0, stream>>>(
            fdg, rij, b_scope, edge_src, W_dist, b_dist, W_gat, a_src,
            tf, W_emb, b_emb, rec, (int*)rec, h_a, h_b, t0v, t1v,
            0, 0, N, 0, 0, 0);
        gat_iter1_fb<<<(N + 7) / 8, 256, 0, stream>>>(t0v, h_b, t1v,
                                                      b_scope, start_env,
                                                      fdg, rij,
                                                      W_dist, b_dist, W_gat,
                                                      a_src, a_dst, N, K);
        const int g2_blocks = ((N + 1) / 2 + 7) / 8;
        gat_iter2<false><<<g2_blocks, 256, 0, stream>>>(h_b, t1v, h_a,
                                                        (const int*)rec, b_scope, start_env,
                                                        edge_src, W_gat, a_dst, N, K);
    }

    readout_kernel<<<(B * 8 + 255) / 256, 256, 0, stream>>>(h_a, l_scope, out, B, L);
}